// Round 5
// baseline (6203.280 us; speedup 1.0000x reference)
//
#include <hip/hip_runtime.h>
#include <hip/hip_bf16.h>

typedef __hip_bfloat16 bf16;

#define Q_LEN 1024
#define B_SZ 4
#define DM 1024
#define H_CNT 16
#define HD 64
#define MEM_LEN 512
#define KLEN 1536
#define MLP 4096

__device__ __forceinline__ float to_f(float x) { return x; }
__device__ __forceinline__ float to_f(bf16 x) { return __bfloat162float(x); }
__device__ __forceinline__ void store_c(float* p, float v) { *p = v; }
__device__ __forceinline__ void store_c(bf16* p, float v) { *p = __float2bfloat16(v); }

// Tiled GEMM: C[M,N] = A[M,K] @ B[K,N] (+bias, optional relu), fp32 accumulate.
// 64x64 tile, 256 threads, 4x4 per thread, BK=16. M%64==0, N%64==0, K%16==0.
template <typename TA, typename TC>
__global__ __launch_bounds__(256) void gemm_kernel(
    const TA* __restrict__ A, const float* __restrict__ B, TC* __restrict__ C,
    int M, int N, int K, const float* __restrict__ bias, int relu) {
  __shared__ float As[16][64];
  __shared__ float Bs[16][64];
  const int tid = threadIdx.x;
  const int row0 = blockIdx.y * 64, col0 = blockIdx.x * 64;
  const int la = tid * 4;
  const int lam = la >> 4, lak = la & 15;   // A tile [m=64][k=16]
  const int lbk = la >> 6, lbn = la & 63;   // B tile [k=16][n=64]
  const int tm = (tid >> 4) * 4, tn = (tid & 15) * 4;
  float acc[4][4] = {};
  for (int k0 = 0; k0 < K; k0 += 16) {
    const TA* ap = A + (size_t)(row0 + lam) * K + k0 + lak;
#pragma unroll
    for (int t = 0; t < 4; ++t) As[lak + t][lam] = to_f(ap[t]);
    const float* bp = B + (size_t)(k0 + lbk) * N + col0 + lbn;
#pragma unroll
    for (int t = 0; t < 4; ++t) Bs[lbk][lbn + t] = bp[t];
    __syncthreads();
#pragma unroll
    for (int k = 0; k < 16; ++k) {
      float a[4], b[4];
#pragma unroll
      for (int x = 0; x < 4; ++x) a[x] = As[k][tm + x];
#pragma unroll
      for (int y = 0; y < 4; ++y) b[y] = Bs[k][tn + y];
#pragma unroll
      for (int x = 0; x < 4; ++x)
#pragma unroll
        for (int y = 0; y < 4; ++y) acc[x][y] += a[x] * b[y];
    }
    __syncthreads();
  }
#pragma unroll
  for (int x = 0; x < 4; ++x) {
#pragma unroll
    for (int y = 0; y < 4; ++y) {
      float v = acc[x][y];
      if (bias) v += bias[col0 + tn + y];
      if (relu) v = v > 0.f ? v : 0.f;
      store_c(&C[(size_t)(row0 + tm + x) * N + col0 + tn + y], v);
    }
  }
}

// Attention: one block per (q-row i, batch b, head h).
// score[i,j] = SCALE * ((q_i+u)·k_j + (q_i+v)·r_h[j-i+Q-1]), valid j <= i+MEM.
// rel-shift garbage region (j-i+Q-1 >= KLEN) == masked region -> analytic mask.
__global__ __launch_bounds__(256) void attn_kernel(
    const bf16* __restrict__ qkv,  // [KLEN*B, 3*DM] rows kk*B+b (ws, bf16)
    const bf16* __restrict__ rh,   // [KLEN, DM] (ws, bf16)
    const float* __restrict__ u, const float* __restrict__ v,
    float* __restrict__ ctx) {     // [Q*B, DM] fp32 (lives in d_out)
  const int i = blockIdx.x, b = blockIdx.y, h = blockIdx.z;
  const int tid = threadIdx.x;
  __shared__ float sc[KLEN];
  __shared__ float qu[HD], qv_s[HD];
  __shared__ float red[256];
  if (tid < HD) {
    float qf = __bfloat162float(
        qkv[((size_t)(i + MEM_LEN) * B_SZ + b) * (3 * DM) + h * HD + tid]);
    qu[tid] = qf + u[h * HD + tid];
    qv_s[tid] = qf + v[h * HD + tid];
  }
  __syncthreads();
  const int nj = i + MEM_LEN + 1;  // valid keys: j in [0, nj)
  for (int j = tid; j < nj; j += 256) {
    const bf16* kp = qkv + ((size_t)j * B_SZ + b) * (3 * DM) + DM + h * HD;
    const bf16* rp = rh + (size_t)(j - i + Q_LEN - 1) * DM + h * HD;
    float s = 0.f;
#pragma unroll 8
    for (int d = 0; d < HD; ++d)
      s += qu[d] * __bfloat162float(kp[d]) + qv_s[d] * __bfloat162float(rp[d]);
    sc[j] = s * 0.125f;
  }
  __syncthreads();
  float lm = -1e30f;
  for (int j = tid; j < nj; j += 256) lm = fmaxf(lm, sc[j]);
  red[tid] = lm;
  __syncthreads();
  for (int s = 128; s > 0; s >>= 1) {
    if (tid < s) red[tid] = fmaxf(red[tid], red[tid + s]);
    __syncthreads();
  }
  const float mx = red[0];
  __syncthreads();
  float ls = 0.f;
  for (int j = tid; j < nj; j += 256) {
    float p = __expf(sc[j] - mx);
    sc[j] = p;
    ls += p;
  }
  red[tid] = ls;
  __syncthreads();
  for (int s = 128; s > 0; s >>= 1) {
    if (tid < s) red[tid] += red[tid + s];
    __syncthreads();
  }
  const float inv = 1.f / red[0];
  __syncthreads();
  const int d = tid & 63, js = tid >> 6;
  const bf16* vp = qkv + (size_t)b * (3 * DM) + 2 * DM + h * HD + d;
  float acc = 0.f;
  for (int j = js; j < nj; j += 4)
    acc += sc[j] * __bfloat162float(vp[(size_t)j * B_SZ * (3 * DM)]);
  red[tid] = acc;
  __syncthreads();
  if (tid < HD) {
    float sv = red[tid] + red[tid + 64] + red[tid + 128] + red[tid + 192];
    ctx[((size_t)i * B_SZ + b) * DM + h * HD + tid] = sv * inv;
  }
}

// LN1: x = LayerNorm(y + inputs) * g + beta   (y bf16 ws; x fp32 ws)
__global__ __launch_bounds__(256) void ln1_kernel(
    const bf16* __restrict__ y, const float* __restrict__ inp,
    const float* __restrict__ g, const float* __restrict__ beta,
    float* __restrict__ xo) {
  const int r = blockIdx.x, tid = threadIdx.x;
  __shared__ float red[256];
  float t[4];
  float s = 0.f;
#pragma unroll
  for (int q = 0; q < 4; ++q) {
    int c = tid + q * 256;
    t[q] = __bfloat162float(y[(size_t)r * DM + c]) + inp[(size_t)r * DM + c];
    s += t[q];
  }
  red[tid] = s;
  __syncthreads();
  for (int st = 128; st > 0; st >>= 1) {
    if (tid < st) red[tid] += red[tid + st];
    __syncthreads();
  }
  const float mean = red[0] * (1.f / DM);
  __syncthreads();
  float vs = 0.f;
#pragma unroll
  for (int q = 0; q < 4; ++q) {
    float d0 = t[q] - mean;
    vs += d0 * d0;
  }
  red[tid] = vs;
  __syncthreads();
  for (int st = 128; st > 0; st >>= 1) {
    if (tid < st) red[tid] += red[tid + st];
    __syncthreads();
  }
  const float rstd = rsqrtf(red[0] * (1.f / DM) + 1e-5f);
#pragma unroll
  for (int q = 0; q < 4; ++q) {
    int c = tid + q * 256;
    xo[(size_t)r * DM + c] = (t[q] - mean) * rstd * g[c] + beta[c];
  }
}

// LN2: out = LayerNorm(x + y2 + b2) * g + beta   (x fp32, y2 bf16; OUT FP32)
__global__ __launch_bounds__(256) void ln2_kernel(
    const float* __restrict__ x, const bf16* __restrict__ y2,
    const float* __restrict__ b2, const float* __restrict__ g,
    const float* __restrict__ beta, float* __restrict__ out) {
  const int r = blockIdx.x, tid = threadIdx.x;
  __shared__ float red[256];
  float t[4];
  float s = 0.f;
#pragma unroll
  for (int q = 0; q < 4; ++q) {
    int c = tid + q * 256;
    t[q] = x[(size_t)r * DM + c] + __bfloat162float(y2[(size_t)r * DM + c]) + b2[c];
    s += t[q];
  }
  red[tid] = s;
  __syncthreads();
  for (int st = 128; st > 0; st >>= 1) {
    if (tid < st) red[tid] += red[tid + st];
    __syncthreads();
  }
  const float mean = red[0] * (1.f / DM);
  __syncthreads();
  float vs = 0.f;
#pragma unroll
  for (int q = 0; q < 4; ++q) {
    float d0 = t[q] - mean;
    vs += d0 * d0;
  }
  red[tid] = vs;
  __syncthreads();
  for (int st = 128; st > 0; st >>= 1) {
    if (tid < st) red[tid] += red[tid + st];
    __syncthreads();
  }
  const float rstd = rsqrtf(red[0] * (1.f / DM) + 1e-5f);
#pragma unroll
  for (int q = 0; q < 4; ++q) {
    int c = tid + q * 256;
    out[(size_t)r * DM + c] = (t[q] - mean) * rstd * g[c] + beta[c];
  }
}

extern "C" void kernel_launch(void* const* d_in, const int* in_sizes, int n_in,
                              void* d_out, int out_size, void* d_ws, size_t ws_size,
                              hipStream_t stream) {
  // Inputs are fp32 (confirmed: device-side bf16 probe fired as "fp32" across
  // rounds). Output is fp32 (reference returns fp32; writing bf16 reproduced
  // the exact deterministic absmax=7.5 signature). Mask may or may not be
  // passed: n_in>=17 -> it's d_in[5]; else weights start at index 5.
  const int o = (n_in >= 17) ? 1 : 0;
  const float* inputs = (const float*)d_in[0];
  const float* r      = (const float*)d_in[1];
  const float* u      = (const float*)d_in[2];
  const float* v      = (const float*)d_in[3];
  const float* memp   = (const float*)d_in[4];
  const float* W_qkv  = (const float*)d_in[5 + o];
  const float* W_r    = (const float*)d_in[6 + o];
  const float* W_o    = (const float*)d_in[7 + o];
  const float* ln1_g  = (const float*)d_in[8 + o];
  const float* ln1_b  = (const float*)d_in[9 + o];
  const float* ln2_g  = (const float*)d_in[10 + o];
  const float* ln2_b  = (const float*)d_in[11 + o];
  const float* W1     = (const float*)d_in[12 + o];
  const float* b1     = (const float*)d_in[13 + o];
  const float* W2     = (const float*)d_in[14 + o];
  const float* b2     = (const float*)d_in[15 + o];

  // Workspace (peak 58,720,256 B):
  //   qkv bf16 [0, 37,748,736)            dead after attn
  //   rh  bf16 [37,748,736, 40,894,464)   dead after attn
  //   ctx fp32 -> d_out (16 MB exactly; dead before LN2 overwrites d_out)
  //   y   bf16 [40,894,464, 49,283,072)   dead after ln1
  //   x   fp32 [0, 16,777,216)            written by ln1 (qkv dead)
  //   hbuf bf16 [16,777,216, 50,331,648)  written after ln1 (rh/y dead)
  //   y2  bf16 [50,331,648, 58,720,256)
  char* ws = (char*)d_ws;
  bf16* qkv   = (bf16*)(ws);
  bf16* rh    = (bf16*)(ws + 37748736);
  float* ctx  = (float*)d_out;
  bf16* y     = (bf16*)(ws + 40894464);
  float* x    = (float*)(ws);
  bf16* hbuf  = (bf16*)(ws + 16777216);
  bf16* y2    = (bf16*)(ws + 50331648);

  dim3 blk(256);
  // qkv = concat(mem, inputs) @ W_qkv  (two launches, no concat copy)
  gemm_kernel<float, bf16><<<dim3(48, 32), blk, 0, stream>>>(
      memp, W_qkv, qkv, 2048, 3072, 1024, nullptr, 0);
  gemm_kernel<float, bf16><<<dim3(48, 64), blk, 0, stream>>>(
      inputs, W_qkv, qkv + (size_t)2048 * 3072, 4096, 3072, 1024, nullptr, 0);
  // r_h = r @ W_r
  gemm_kernel<float, bf16><<<dim3(16, 24), blk, 0, stream>>>(
      r, W_r, rh, 1536, 1024, 1024, nullptr, 0);
  // attention -> ctx (fp32, in d_out)
  attn_kernel<<<dim3(1024, 4, 16), blk, 0, stream>>>(qkv, rh, u, v, ctx);
  // y = ctx @ W_o
  gemm_kernel<float, bf16><<<dim3(16, 64), blk, 0, stream>>>(
      ctx, W_o, y, 4096, 1024, 1024, nullptr, 0);
  // x = LN1(inputs + y)
  ln1_kernel<<<dim3(4096), blk, 0, stream>>>(y, inputs, ln1_g, ln1_b, x);
  // h = relu(x @ W1 + b1)
  gemm_kernel<float, bf16><<<dim3(64, 64), blk, 0, stream>>>(
      x, W1, hbuf, 4096, 4096, 1024, b1, 1);
  // y2 = h @ W2
  gemm_kernel<bf16, bf16><<<dim3(16, 64), blk, 0, stream>>>(
      hbuf, W2, y2, 4096, 1024, 4096, nullptr, 0);
  // out = LN2(x + y2 + b2)  -> fp32 d_out (ctx dead)
  ln2_kernel<<<dim3(4096), blk, 0, stream>>>(x, y2, b2, ln2_g, ln2_b, (float*)d_out);
}

// Round 7
// 2158.470 us; speedup vs baseline: 2.8739x; 2.8739x over previous
//
#include <hip/hip_runtime.h>
#include <hip/hip_bf16.h>

typedef __hip_bfloat16 bf16;
typedef __attribute__((ext_vector_type(8))) short short8;
typedef __attribute__((ext_vector_type(4))) float f32x4;

#define Q_LEN 1024
#define B_SZ 4
#define DM 1024
#define H_CNT 16
#define HD 64
#define MEM_LEN 512
#define KLEN 1536
#define MLP 4096

__device__ __forceinline__ float to_f(float x) { return x; }
__device__ __forceinline__ float to_f(bf16 x) { return __bfloat162float(x); }
__device__ __forceinline__ void store_c(float* p, float v) { *p = v; }
__device__ __forceinline__ void store_c(bf16* p, float v) { *p = __float2bfloat16(v); }

__device__ __forceinline__ float b2f(short s) {
  union { unsigned u; float f; } x;
  x.u = ((unsigned)(unsigned short)s) << 16;
  return x.f;
}
__device__ __forceinline__ short f2b(float f) {
  union { float f; unsigned u; } x;
  x.f = f;
  unsigned r = x.u + 0x7fff + ((x.u >> 16) & 1);  // RNE; inputs finite
  return (short)(r >> 16);
}

// ---------------- GEMM (unchanged from R5, passing) ----------------
template <typename TA, typename TC>
__global__ __launch_bounds__(256) void gemm_kernel(
    const TA* __restrict__ A, const float* __restrict__ B, TC* __restrict__ C,
    int M, int N, int K, const float* __restrict__ bias, int relu) {
  __shared__ float As[16][64];
  __shared__ float Bs[16][64];
  const int tid = threadIdx.x;
  const int row0 = blockIdx.y * 64, col0 = blockIdx.x * 64;
  const int la = tid * 4;
  const int lam = la >> 4, lak = la & 15;
  const int lbk = la >> 6, lbn = la & 63;
  const int tm = (tid >> 4) * 4, tn = (tid & 15) * 4;
  float acc[4][4] = {};
  for (int k0 = 0; k0 < K; k0 += 16) {
    const TA* ap = A + (size_t)(row0 + lam) * K + k0 + lak;
#pragma unroll
    for (int t = 0; t < 4; ++t) As[lak + t][lam] = to_f(ap[t]);
    const float* bp = B + (size_t)(k0 + lbk) * N + col0 + lbn;
#pragma unroll
    for (int t = 0; t < 4; ++t) Bs[lbk][lbn + t] = bp[t];
    __syncthreads();
#pragma unroll
    for (int k = 0; k < 16; ++k) {
      float a[4], b[4];
#pragma unroll
      for (int x = 0; x < 4; ++x) a[x] = As[k][tm + x];
#pragma unroll
      for (int y = 0; y < 4; ++y) b[y] = Bs[k][tn + y];
#pragma unroll
      for (int x = 0; x < 4; ++x)
#pragma unroll
        for (int y = 0; y < 4; ++y) acc[x][y] += a[x] * b[y];
    }
    __syncthreads();
  }
#pragma unroll
  for (int x = 0; x < 4; ++x) {
#pragma unroll
    for (int y = 0; y < 4; ++y) {
      float v = acc[x][y];
      if (bias) v += bias[col0 + tn + y];
      if (relu) v = v > 0.f ? v : 0.f;
      store_c(&C[(size_t)(row0 + tm + x) * N + col0 + tn + y], v);
    }
  }
}

// ---------------- Fused flash-MFMA attention ----------------
// Block: 64-query tile for one (b,h). 4 waves; wave w owns q-strip rows
// [w*16, w*16+16). K-loop over 32-key tiles with online softmax.
// score[i][j] = SCALE*((q_i+u)·k_j + (q_i+u)·r_t + (v-u)·r_t), t=j-i+1023;
// mask j>i+512 (== rel-shift garbage region).
// MFMA 16x16x32_bf16 layouts (m89/m91-verified):
//   A[m=lane&15][k=quad*8+jj], B[k=quad*8+jj][n=lane&15],
//   C/D: col=lane&15, row=quad*4+reg.
__global__ __launch_bounds__(256, 3) void fattn_kernel(
    const bf16* __restrict__ qkvp,  // [1536*4, 3072] rows k*B+b, bf16
    const bf16* __restrict__ rhp,   // [1536, 1024] bf16
    const float* __restrict__ u, const float* __restrict__ v,
    float* __restrict__ ctx) {      // [4096, 1024] fp32 (in d_out)
  const int i0 = blockIdx.x * 64;
  const int b = blockIdx.y, h = blockIdx.z;
  const int tid = threadIdx.x;
  const int w = tid >> 6, lane = tid & 63;
  const int quad = lane >> 4, m16 = lane & 15;

  __shared__ short sQu[64 * 72];   // (q+u) tile, bf16, row stride 72
  __shared__ short sK[32 * 72];    // K tile
  __shared__ short sVt[64 * 40];   // V^T tile: [d][j]
  __shared__ short sR[96 * 72];    // R window, block trel = j_loc-i_loc+63
  __shared__ short sProb[64 * 40]; // probs bf16, per-wave 16x32 strips
  __shared__ float sPm[64 * 48];   // P (=Qu·r + vr) fp32, per-wave strips
  __shared__ float vr_s[96];       // (v-u)·r_t per staged row
  __shared__ float su_s[64];       // u[h]
  __shared__ float wv_s[64];       // v[h]-u[h]

  const short* qkv = (const short*)qkvp;
  const short* rh  = (const short*)rhp;

  if (tid < 64) su_s[tid] = u[h * 64 + tid];
  else if (tid < 128) wv_s[tid - 64] = v[h * 64 + (tid - 64)] - u[h * 64 + (tid - 64)];
  __syncthreads();

  // Stage Qu = q + u (bf16), rows i0..i0+63 (q row = qkv row i+512)
  {
    const int row_ = tid >> 3, d0 = (tid & 7) * 8;
#pragma unroll
    for (int p = 0; p < 2; ++p) {
      const int row = p * 32 + row_;
      short8 q8 = *(const short8*)&qkv[((size_t)(512 + i0 + row) * 4 + b) * 3072 + h * 64 + d0];
      short8 o;
#pragma unroll
      for (int q = 0; q < 8; ++q) o[q] = f2b(b2f(q8[q]) + su_s[d0 + q]);
      *(short8*)&sQu[row * 72 + d0] = o;
    }
  }
  __syncthreads();

  const short8 aQu0 = *(const short8*)&sQu[(w * 16 + m16) * 72 + quad * 8];
  const short8 aQu1 = *(const short8*)&sQu[(w * 16 + m16) * 72 + 32 + quad * 8];

  f32x4 O[4] = {};
  float m_r[4] = {-1e30f, -1e30f, -1e30f, -1e30f};
  float l_r[4] = {0.f, 0.f, 0.f, 0.f};

  const int n_kt = ((i0 + 575) >> 5) + 1;  // valid j <= i+512, i <= i0+63
  for (int kt = 0; kt < n_kt; ++kt) {
    const int j0 = kt * 32;
    const int tbase = j0 - i0 + 960;  // t = tbase + trel, trel in [0,95]
    __syncthreads();  // previous tile's reads complete before restage

    // K tile: 32 rows x 64 d
    {
      const int row = tid >> 3, d0 = (tid & 7) * 8;
      *(short8*)&sK[row * 72 + d0] =
          *(const short8*)&qkv[((size_t)(j0 + row) * 4 + b) * 3072 + 1024 + h * 64 + d0];
    }
    // V^T tile: wave-uniform d (2-way-conflict scattered writes)
    {
      const int j = lane & 31, d0 = w * 16 + (lane >> 5) * 8;
      short8 v8 = *(const short8*)&qkv[((size_t)(j0 + j) * 4 + b) * 3072 + 2048 + h * 64 + d0];
#pragma unroll
      for (int q = 0; q < 8; ++q) sVt[(d0 + q) * 40 + j] = v8[q];
    }
    // R window (96 rows) + vr = (v-u)·r_t
    {
      const int row_ = tid >> 3, d0 = (tid & 7) * 8;
#pragma unroll
      for (int p = 0; p < 3; ++p) {
        const int row = p * 32 + row_;
        int t = tbase + row;
        t = t < 0 ? 0 : (t > 1535 ? 1535 : t);  // clamped rows only feed masked elems
        short8 r8 = *(const short8*)&rh[(size_t)t * 1024 + h * 64 + d0];
        *(short8*)&sR[row * 72 + d0] = r8;
        float part = 0.f;
#pragma unroll
        for (int q = 0; q < 8; ++q) part += wv_s[d0 + q] * b2f(r8[q]);
        part += __shfl_xor(part, 1);
        part += __shfl_xor(part, 2);
        part += __shfl_xor(part, 4);
        if ((tid & 7) == 0) vr_s[row] = part;
      }
    }
    __syncthreads();

    // P tiles: wave trel window [48-16w, 94-16w] -> 3 tiles of 16
#pragma unroll
    for (int pt = 0; pt < 3; ++pt) {
      const int p0 = 48 - 16 * w + 16 * pt;
      short8 bR0 = *(const short8*)&sR[(p0 + m16) * 72 + quad * 8];
      short8 bR1 = *(const short8*)&sR[(p0 + m16) * 72 + 32 + quad * 8];
      f32x4 pf = {};
      pf = __builtin_amdgcn_mfma_f32_16x16x32_bf16(aQu0, bR0, pf, 0, 0, 0);
      pf = __builtin_amdgcn_mfma_f32_16x16x32_bf16(aQu1, bR1, pf, 0, 0, 0);
      const float vrv = vr_s[p0 + m16];
#pragma unroll
      for (int rg = 0; rg < 4; ++rg)
        sPm[(w * 16 + quad * 4 + rg) * 48 + pt * 16 + m16] = pf[rg] + vrv;
    }
    // AC tiles: 2 subtiles of 16 key-cols
    f32x4 ac[2];
#pragma unroll
    for (int n0i = 0; n0i < 2; ++n0i) {
      short8 bK0 = *(const short8*)&sK[(n0i * 16 + m16) * 72 + quad * 8];
      short8 bK1 = *(const short8*)&sK[(n0i * 16 + m16) * 72 + 32 + quad * 8];
      f32x4 a = {};
      a = __builtin_amdgcn_mfma_f32_16x16x32_bf16(aQu0, bK0, a, 0, 0, 0);
      a = __builtin_amdgcn_mfma_f32_16x16x32_bf16(aQu1, bK1, a, 0, 0, 0);
      ac[n0i] = a;
    }
    // Scores + online softmax (state per lane covers rows quad*4+rg)
#pragma unroll
    for (int rg = 0; rg < 4; ++rg) {
      const int rloc = quad * 4 + rg;
      const int irow = i0 + w * 16 + rloc;
      const int c0 = m16 - rloc + 15;  // rel-shift read offset, in [0,30]
      const float p0v = sPm[(w * 16 + rloc) * 48 + c0];
      const float p1v = sPm[(w * 16 + rloc) * 48 + c0 + 16];
      float s0 = (ac[0][rg] + p0v) * 0.125f;
      float s1 = (ac[1][rg] + p1v) * 0.125f;
      if (j0 + m16 > irow + 512) s0 = -1e30f;
      if (j0 + 16 + m16 > irow + 512) s1 = -1e30f;
      float mx = fmaxf(s0, s1);
      mx = fmaxf(mx, __shfl_xor(mx, 1));
      mx = fmaxf(mx, __shfl_xor(mx, 2));
      mx = fmaxf(mx, __shfl_xor(mx, 4));
      mx = fmaxf(mx, __shfl_xor(mx, 8));
      const float mnew = fmaxf(m_r[rg], mx);
      const float al = __expf(m_r[rg] - mnew);
      const float e0 = __expf(s0 - mnew);
      const float e1 = __expf(s1 - mnew);
      float rs = e0 + e1;
      rs += __shfl_xor(rs, 1);
      rs += __shfl_xor(rs, 2);
      rs += __shfl_xor(rs, 4);
      rs += __shfl_xor(rs, 8);
      m_r[rg] = mnew;
      l_r[rg] = l_r[rg] * al + rs;
      sProb[(w * 16 + rloc) * 40 + m16] = f2b(e0);
      sProb[(w * 16 + rloc) * 40 + 16 + m16] = f2b(e1);
#pragma unroll
      for (int d0i = 0; d0i < 4; ++d0i) O[d0i][rg] *= al;
    }
    // PV: A from probs (k=32 -> one frag), B from V^T
    const short8 aP = *(const short8*)&sProb[(w * 16 + m16) * 40 + quad * 8];
#pragma unroll
    for (int d0i = 0; d0i < 4; ++d0i) {
      short8 bV = *(const short8*)&sVt[(d0i * 16 + m16) * 40 + quad * 8];
      O[d0i] = __builtin_amdgcn_mfma_f32_16x16x32_bf16(aP, bV, O[d0i], 0, 0, 0);
    }
  }
  // Epilogue: ctx[i*B+b][h*64+d] = O/l
#pragma unroll
  for (int d0i = 0; d0i < 4; ++d0i) {
#pragma unroll
    for (int rg = 0; rg < 4; ++rg) {
      const int irow = i0 + w * 16 + quad * 4 + rg;
      ctx[((size_t)irow * 4 + b) * 1024 + h * 64 + d0i * 16 + m16] = O[d0i][rg] / l_r[rg];
    }
  }
}

// ---------------- LayerNorms (unchanged from R5, passing) ----------------
__global__ __launch_bounds__(256) void ln1_kernel(
    const bf16* __restrict__ y, const float* __restrict__ inp,
    const float* __restrict__ g, const float* __restrict__ beta,
    float* __restrict__ xo) {
  const int r = blockIdx.x, tid = threadIdx.x;
  __shared__ float red[256];
  float t[4];
  float s = 0.f;
#pragma unroll
  for (int q = 0; q < 4; ++q) {
    int c = tid + q * 256;
    t[q] = __bfloat162float(y[(size_t)r * DM + c]) + inp[(size_t)r * DM + c];
    s += t[q];
  }
  red[tid] = s;
  __syncthreads();
  for (int st = 128; st > 0; st >>= 1) {
    if (tid < st) red[tid] += red[tid + st];
    __syncthreads();
  }
  const float mean = red[0] * (1.f / DM);
  __syncthreads();
  float vs = 0.f;
#pragma unroll
  for (int q = 0; q < 4; ++q) {
    float d0 = t[q] - mean;
    vs += d0 * d0;
  }
  red[tid] = vs;
  __syncthreads();
  for (int st = 128; st > 0; st >>= 1) {
    if (tid < st) red[tid] += red[tid + st];
    __syncthreads();
  }
  const float rstd = rsqrtf(red[0] * (1.f / DM) + 1e-5f);
#pragma unroll
  for (int q = 0; q < 4; ++q) {
    int c = tid + q * 256;
    xo[(size_t)r * DM + c] = (t[q] - mean) * rstd * g[c] + beta[c];
  }
}

__global__ __launch_bounds__(256) void ln2_kernel(
    const float* __restrict__ x, const bf16* __restrict__ y2,
    const float* __restrict__ b2, const float* __restrict__ g,
    const float* __restrict__ beta, float* __restrict__ out) {
  const int r = blockIdx.x, tid = threadIdx.x;
  __shared__ float red[256];
  float t[4];
  float s = 0.f;
#pragma unroll
  for (int q = 0; q < 4; ++q) {
    int c = tid + q * 256;
    t[q] = x[(size_t)r * DM + c] + __bfloat162float(y2[(size_t)r * DM + c]) + b2[c];
    s += t[q];
  }
  red[tid] = s;
  __syncthreads();
  for (int st = 128; st > 0; st >>= 1) {
    if (tid < st) red[tid] += red[tid + st];
    __syncthreads();
  }
  const float mean = red[0] * (1.f / DM);
  __syncthreads();
  float vs = 0.f;
#pragma unroll
  for (int q = 0; q < 4; ++q) {
    float d0 = t[q] - mean;
    vs += d0 * d0;
  }
  red[tid] = vs;
  __syncthreads();
  for (int st = 128; st > 0; st >>= 1) {
    if (tid < st) red[tid] += red[tid + st];
    __syncthreads();
  }
  const float rstd = rsqrtf(red[0] * (1.f / DM) + 1e-5f);
#pragma unroll
  for (int q = 0; q < 4; ++q) {
    int c = tid + q * 256;
    out[(size_t)r * DM + c] = (t[q] - mean) * rstd * g[c] + beta[c];
  }
}

extern "C" void kernel_launch(void* const* d_in, const int* in_sizes, int n_in,
                              void* d_out, int out_size, void* d_ws, size_t ws_size,
                              hipStream_t stream) {
  const int o = (n_in >= 17) ? 1 : 0;
  const float* inputs = (const float*)d_in[0];
  const float* r      = (const float*)d_in[1];
  const float* u      = (const float*)d_in[2];
  const float* v      = (const float*)d_in[3];
  const float* memp   = (const float*)d_in[4];
  const float* W_qkv  = (const float*)d_in[5 + o];
  const float* W_r    = (const float*)d_in[6 + o];
  const float* W_o    = (const float*)d_in[7 + o];
  const float* ln1_g  = (const float*)d_in[8 + o];
  const float* ln1_b  = (const float*)d_in[9 + o];
  const float* ln2_g  = (const float*)d_in[10 + o];
  const float* ln2_b  = (const float*)d_in[11 + o];
  const float* W1     = (const float*)d_in[12 + o];
  const float* b1     = (const float*)d_in[13 + o];
  const float* W2     = (const float*)d_in[14 + o];
  const float* b2     = (const float*)d_in[15 + o];

  // Workspace (peak 58,720,256 B) — same layout as R5 (passing)
  char* ws = (char*)d_ws;
  bf16* qkv   = (bf16*)(ws);
  bf16* rh    = (bf16*)(ws + 37748736);
  float* ctx  = (float*)d_out;
  bf16* y     = (bf16*)(ws + 40894464);
  float* x    = (float*)(ws);
  bf16* hbuf  = (bf16*)(ws + 16777216);
  bf16* y2    = (bf16*)(ws + 50331648);

  dim3 blk(256);
  gemm_kernel<float, bf16><<<dim3(48, 32), blk, 0, stream>>>(
      memp, W_qkv, qkv, 2048, 3072, 1024, nullptr, 0);
  gemm_kernel<float, bf16><<<dim3(48, 64), blk, 0, stream>>>(
      inputs, W_qkv, qkv + (size_t)2048 * 3072, 4096, 3072, 1024, nullptr, 0);
  gemm_kernel<float, bf16><<<dim3(16, 24), blk, 0, stream>>>(
      r, W_r, rh, 1536, 1024, 1024, nullptr, 0);
  // fused flash-MFMA attention -> ctx (fp32, in d_out)
  fattn_kernel<<<dim3(16, 4, 16), blk, 0, stream>>>(qkv, rh, u, v, ctx);
  gemm_kernel<float, bf16><<<dim3(16, 64), blk, 0, stream>>>(
      ctx, W_o, y, 4096, 1024, 1024, nullptr, 0);
  ln1_kernel<<<dim3(4096), blk, 0, stream>>>(y, inputs, ln1_g, ln1_b, x);
  gemm_kernel<float, bf16><<<dim3(64, 64), blk, 0, stream>>>(
      x, W1, hbuf, 4096, 4096, 1024, b1, 1);
  gemm_kernel<bf16, bf16><<<dim3(16, 64), blk, 0, stream>>>(
      hbuf, W2, y2, 4096, 1024, 4096, nullptr, 0);
  ln2_kernel<<<dim3(4096), blk, 0, stream>>>(x, y2, b2, ln2_g, ln2_b, (float*)d_out);
}